// Round 1
// baseline (4037.609 us; speedup 1.0000x reference)
//
#include <hip/hip_runtime.h>

typedef _Float16 f16;
typedef _Float16 f16x8 __attribute__((ext_vector_type(8)));
typedef float f32x4 __attribute__((ext_vector_type(4)));

// dims
#define BB 128
#define TT 128
#define IIN 512
#define HHID 512
#define EEX 256

// ---------------- prep: fp32 -> fp16 conversions + counter reset ----------------
__global__ void prep_kernel(const float* __restrict__ x,
    const float* __restrict__ W_ir, const float* __restrict__ W_iz, const float* __restrict__ W_in,
    const float* __restrict__ W_hr, const float* __restrict__ W_hz, const float* __restrict__ W_hn,
    f16* __restrict__ xb, f16* __restrict__ WiCat, f16* __restrict__ WhCat,
    unsigned* __restrict__ cnt)
{
  size_t idx = (size_t)blockIdx.x * 256 + threadIdx.x;
  if (blockIdx.x == 0 && threadIdx.x < 16) cnt[threadIdx.x] = 0u;

  const size_t NX = (size_t)TT * BB * (IIN / 8);         // 1,048,576 chunks of 8
  const size_t NW = (size_t)2 * 1536 * (512 / 8);        // 196,608 per weight set
  if (idx < NX) {
    int t = (int)(idx / (BB * 64));
    int rem = (int)(idx % (BB * 64));
    int b = rem >> 6;
    int k0 = (rem & 63) * 8;
    const float* src = x + ((size_t)b * TT + t) * IIN + k0;
    f16x8 v;
#pragma unroll
    for (int j = 0; j < 8; ++j) v[j] = (f16)src[j];
    *(f16x8*)(xb + ((size_t)t * BB + b) * IIN + k0) = v;
  } else if (idx < NX + 2 * NW) {
    size_t w = idx - NX;
    bool isI = w < NW;
    size_t w2 = isI ? w : w - NW;
    int l = (int)(w2 / (1536 * 64));
    int rem = (int)(w2 % (1536 * 64));
    int n = rem >> 6;
    int k0 = (rem & 63) * 8;
    int g = n >> 9, j = n & 511;
    const float* W = isI ? (g == 0 ? W_ir : (g == 1 ? W_iz : W_in))
                         : (g == 0 ? W_hr : (g == 1 ? W_hz : W_hn));
    const float* src = W + ((size_t)l * 512 + j) * 512 + k0;
    f16x8 v;
#pragma unroll
    for (int jj = 0; jj < 8; ++jj) v[jj] = (f16)src[jj];
    f16* dst = isI ? WiCat : WhCat;
    *(f16x8*)(dst + ((size_t)l * 1536 + n) * 512 + k0) = v;
  }
}

// ---------------- er[l][b][h] = sum_e extra[b][e] * W_er[l][h][e] (f32) ----------------
__global__ void er_kernel(const float* __restrict__ extra, const float* __restrict__ W_er,
                          float* __restrict__ er)
{
  int idx = blockIdx.x * 256 + threadIdx.x;   // 2*128*512 = 131072
  int l = idx >> 16;
  int b = (idx >> 9) & 127;
  int h = idx & 511;
  const float* e = extra + (size_t)b * EEX;
  const float* w = W_er + ((size_t)l * 512 + h) * EEX;
  float acc = 0.f;
#pragma unroll 4
  for (int k = 0; k < EEX; k += 4)
    acc += e[k] * w[k] + e[k + 1] * w[k + 1] + e[k + 2] * w[k + 2] + e[k + 3] * w[k + 3];
  er[idx] = acc;
}

// ---------------- input-projection GEMM: Gi[m][n] = A[m,:] . Wcat[n,:] + bias + er ----------------
// M=16384 (m = t*128+b), N=1536, K=512. A,Wcat row-major fp16 (K contiguous). Output fp16.
__global__ __launch_bounds__(256, 2) void gemm_gi(
    const f16* __restrict__ A, const f16* __restrict__ Wcat,
    const float* __restrict__ b_r, const float* __restrict__ b_z, const float* __restrict__ b_n,
    const float* __restrict__ er,    // [128][512] this layer
    f16* __restrict__ Gi)            // [16384][1536]
{
  const int tid = threadIdx.x;
  const int wave = tid >> 6, lane = tid & 63;
  const int bm = blockIdx.x % 128, bn = blockIdx.x / 128;  // 128 x 12 tiles
  const int m0 = bm * 128, n0 = bn * 128;
  const int wm = wave >> 1, wn = wave & 1;
  const int r16 = lane & 15, khi = lane >> 4;

  __shared__ f16 As[128 * 40];   // padded stride 40 f16
  __shared__ f16 Bs[128 * 40];

  const f32x4 vzero = {0.f, 0.f, 0.f, 0.f};
  f32x4 acc[4][4];
#pragma unroll
  for (int mi = 0; mi < 4; ++mi)
#pragma unroll
    for (int ni = 0; ni < 4; ++ni) acc[mi][ni] = vzero;

  const int srow = tid >> 1, skoff = (tid & 1) * 16;
  const f16* Aptr = A + (size_t)(m0 + srow) * 512 + skoff;
  const f16* Bptr = Wcat + (size_t)(n0 + srow) * 512 + skoff;

  for (int ks = 0; ks < 512; ks += 32) {
    f16x8 a0 = *(const f16x8*)(Aptr + ks);
    f16x8 a1 = *(const f16x8*)(Aptr + ks + 8);
    f16x8 b0 = *(const f16x8*)(Bptr + ks);
    f16x8 b1 = *(const f16x8*)(Bptr + ks + 8);
    *(f16x8*)(As + srow * 40 + skoff)     = a0;
    *(f16x8*)(As + srow * 40 + skoff + 8) = a1;
    *(f16x8*)(Bs + srow * 40 + skoff)     = b0;
    *(f16x8*)(Bs + srow * 40 + skoff + 8) = b1;
    __syncthreads();
    f16x8 af[4], bf[4];
#pragma unroll
    for (int mi = 0; mi < 4; ++mi)
      af[mi] = *(const f16x8*)(As + (wm * 64 + mi * 16 + r16) * 40 + khi * 8);
#pragma unroll
    for (int ni = 0; ni < 4; ++ni)
      bf[ni] = *(const f16x8*)(Bs + (wn * 64 + ni * 16 + r16) * 40 + khi * 8);
#pragma unroll
    for (int mi = 0; mi < 4; ++mi)
#pragma unroll
      for (int ni = 0; ni < 4; ++ni)
        acc[mi][ni] = __builtin_amdgcn_mfma_f32_16x16x32_f16(af[mi], bf[ni], acc[mi][ni], 0, 0, 0);
    __syncthreads();
  }

  // epilogue: C/D layout col = lane&15, row = (lane>>4)*4 + v  [m89 verified]
#pragma unroll
  for (int mi = 0; mi < 4; ++mi) {
#pragma unroll
    for (int v = 0; v < 4; ++v) {
      int gm = m0 + wm * 64 + mi * 16 + khi * 4 + v;
      int b = gm & 127;
#pragma unroll
      for (int ni = 0; ni < 4; ++ni) {
        int gn = n0 + wn * 64 + ni * 16 + r16;
        int j = gn & 511;
        float bias, add = 0.f;
        if (gn < 512)       { bias = b_r[j]; add = er[(size_t)b * 512 + j]; }
        else if (gn < 1024) { bias = b_z[j]; }
        else                { bias = b_n[j]; }
        float val = acc[mi][ni][v] + bias + add;
        Gi[(size_t)gm * 1536 + gn] = (f16)val;
      }
    }
  }
}

// ---------------- recurrence: 8 clusters (16 rows) x 8 col-slice blocks (64 hid cols) ----------------
__global__ __launch_bounds__(384, 1) void recur_kernel(
    const f16* __restrict__ Whcat,   // [1536][512] this layer
    const f16* __restrict__ Gi,      // [16384][1536] fp16
    f16* __restrict__ h0seq,         // layer0: [T*128][512] out (else null)
    float* __restrict__ outs,        // layer1: d_out [128][T][512] (else null)
    float* __restrict__ hfin,        // d_out tail + layer*128*512
    f16* __restrict__ hglob,         // [2][128][512] exchange (fp16)
    unsigned* __restrict__ cnt,      // 8 counters for this layer
    int layer)
{
  const int tid = threadIdx.x;
  const int wave = tid >> 6, lane = tid & 63;
  const int cluster = blockIdx.x & 7;   // row group: rows cluster*16..+15
  const int s = blockIdx.x >> 3;        // col slice: hidden cols s*64..+63
  const int r16 = lane & 15, khi = lane >> 4;

  __shared__ f16 hcur[16 * 520];        // padded (520 f16/row)
  __shared__ float pre[12][16][16];     // 12 gate-col tiles of 16x16
  __shared__ float hf32[16 * 64];       // fp32 master h for own slice

  // weights -> registers (loop-invariant B-fragments). wave handles tiles {wave, wave+6}
  f16x8 wf[2][16];
#pragma unroll
  for (int ti = 0; ti < 2; ++ti) {
    int tau = wave + ti * 6;
    int g = tau >> 2, cb = tau & 3;
    int gcol = g * 512 + s * 64 + cb * 16 + r16;
    const f16* wrow = Whcat + (size_t)gcol * 512 + khi * 8;
#pragma unroll
    for (int c = 0; c < 16; ++c)
      wf[ti][c] = *(const f16x8*)(wrow + c * 32);
  }

  // zero-init h state
  for (int i = tid; i < 16 * 520 / 8; i += 384) {
    f16x8 z;
#pragma unroll
    for (int j = 0; j < 8; ++j) z[j] = (f16)0.f;
    ((f16x8*)hcur)[i] = z;
  }
  for (int i = tid; i < 1024; i += 384) hf32[i] = 0.f;
  __syncthreads();

  // Gi prefetch registers (up to 3 items/thread)
  float pgr[3], pgz[3], pgn[3];
#pragma unroll
  for (int u = 0; u < 3; ++u) { pgr[u] = 0.f; pgz[u] = 0.f; pgn[u] = 0.f; }

  {
    // prefetch t=0
#pragma unroll
    for (int u = 0; u < 3; ++u) {
      int i = tid + u * 384;
      if (i < 1024) {
        int row = i >> 6, j = i & 63;
        size_t gib = ((size_t)(0 * 128 + cluster * 16 + row)) * 1536 + s * 64 + j;
        pgr[u] = (float)Gi[gib];
        pgz[u] = (float)Gi[gib + 512];
        pgn[u] = (float)Gi[gib + 1024];
      }
    }
  }

  for (int t = 0; t < TT; ++t) {
    // ---- MFMA: pre[m, gatecol] = h . Whcat^T ----
    const f32x4 vzero = {0.f, 0.f, 0.f, 0.f};
    f32x4 acc0 = vzero, acc1 = vzero;
#pragma unroll
    for (int c = 0; c < 16; ++c) {
      f16x8 a = *(const f16x8*)(hcur + r16 * 520 + c * 32 + khi * 8);
      acc0 = __builtin_amdgcn_mfma_f32_16x16x32_f16(a, wf[0][c], acc0, 0, 0, 0);
      acc1 = __builtin_amdgcn_mfma_f32_16x16x32_f16(a, wf[1][c], acc1, 0, 0, 0);
    }
    {
      int tau0 = wave, tau1 = wave + 6;
#pragma unroll
      for (int v = 0; v < 4; ++v) pre[tau0][khi * 4 + v][r16] = acc0[v];
#pragma unroll
      for (int v = 0; v < 4; ++v) pre[tau1][khi * 4 + v][r16] = acc1[v];
    }
    __syncthreads();

    // ---- blend: gates + state update ----
#pragma unroll
    for (int u = 0; u < 3; ++u) {
      int i = tid + u * 384;
      if (i < 1024) {
        int row = i >> 6, j = i & 63;
        int gr = cluster * 16 + row;
        float pr = pre[(j >> 4)][row][j & 15];
        float pz = pre[4 + (j >> 4)][row][j & 15];
        float pn = pre[8 + (j >> 4)][row][j & 15];
        float rg = 1.f / (1.f + __expf(-(pgr[u] + pr)));
        float zg = 1.f / (1.f + __expf(-(pgz[u] + pz)));
        float xn = pgn[u] + rg * pn;
        xn = fminf(15.f, fmaxf(-15.f, xn));
        float e2 = __expf(2.f * xn);
        float nn = (e2 - 1.f) / (e2 + 1.f);
        float hold = hf32[i];
        float hnew = (1.f - zg) * nn + zg * hold;
        hf32[i] = hnew;
        int nbuf = (t + 1) & 1;
        hglob[(size_t)nbuf * 65536 + (size_t)gr * 512 + s * 64 + j] = (f16)hnew;
        if (layer == 0)
          h0seq[((size_t)t * 128 + gr) * 512 + s * 64 + j] = (f16)hnew;
        else
          outs[((size_t)gr * TT + t) * 512 + s * 64 + j] = hnew;
        if (t == TT - 1)
          hfin[(size_t)gr * 512 + s * 64 + j] = hnew;
      }
    }
    if (t == TT - 1) break;

    // ---- prefetch Gi[t+1] (independent of h; overlaps barrier wait) ----
#pragma unroll
    for (int u = 0; u < 3; ++u) {
      int i = tid + u * 384;
      if (i < 1024) {
        int row = i >> 6, j = i & 63;
        size_t gib = ((size_t)((t + 1) * 128 + cluster * 16 + row)) * 1536 + s * 64 + j;
        pgr[u] = (float)Gi[gib];
        pgz[u] = (float)Gi[gib + 512];
        pgn[u] = (float)Gi[gib + 1024];
      }
    }

    // ---- cluster barrier (release h slice, acquire full h) ----
    __threadfence();
    __syncthreads();
    if (tid == 0) {
      __hip_atomic_fetch_add(&cnt[cluster], 1u, __ATOMIC_RELEASE, __HIP_MEMORY_SCOPE_AGENT);
      while (__hip_atomic_load(&cnt[cluster], __ATOMIC_ACQUIRE, __HIP_MEMORY_SCOPE_AGENT)
             < 8u * (unsigned)(t + 1))
        __builtin_amdgcn_s_sleep(2);
    }
    __syncthreads();
    __threadfence();   // acquire: invalidate L1 before reading peers' h

    // ---- reload full h (fp16) into LDS ----
    {
      int nbuf = (t + 1) & 1;
      const f16* src = hglob + (size_t)nbuf * 65536 + (size_t)cluster * 16 * 512;
      for (int c = tid; c < 1024; c += 384) {
        int row = c >> 6, off = (c & 63) * 8;
        *(f16x8*)(hcur + row * 520 + off) = *(const f16x8*)(src + (size_t)row * 512 + off);
      }
    }
    __syncthreads();
  }
}

// ---------------- launcher ----------------
extern "C" void kernel_launch(void* const* d_in, const int* in_sizes, int n_in,
                              void* d_out, int out_size, void* d_ws, size_t ws_size,
                              hipStream_t stream) {
  const float* x     = (const float*)d_in[0];
  const float* extra = (const float*)d_in[1];
  const float* W_ir  = (const float*)d_in[2];
  const float* b_ir  = (const float*)d_in[3];
  const float* W_hr  = (const float*)d_in[4];
  const float* W_iz  = (const float*)d_in[5];
  const float* b_iz  = (const float*)d_in[6];
  const float* W_hz  = (const float*)d_in[7];
  const float* W_in  = (const float*)d_in[8];
  const float* b_in  = (const float*)d_in[9];
  const float* W_hn  = (const float*)d_in[10];
  const float* W_er  = (const float*)d_in[11];
  float* out = (float*)d_out;

  char* ws = (char*)d_ws;
  f16* WiCat   = (f16*)(ws);                   // 2*1536*512 fp16 = 3,145,728 B
  f16* WhCat   = (f16*)(ws + 3145728);         // 3,145,728 B
  f16* xb      = (f16*)(ws + 6291456);         // 16,777,216 B
  f16* h0seq   = (f16*)(ws + 23068672);        // 16,777,216 B
  float* er    = (float*)(ws + 39845888);      // 524,288 B
  f16* Gi      = (f16*)(ws + 40370176);        // 16384*1536*2 = 50,331,648 B
  f16* hglob   = (f16*)(ws + 90701824);        // 262,144 B
  unsigned* cnt = (unsigned*)(ws + 90963968);  // 64 B   (total ~91 MB)

  prep_kernel<<<5632, 256, 0, stream>>>(x, W_ir, W_iz, W_in, W_hr, W_hz, W_hn,
                                        xb, WiCat, WhCat, cnt);
  er_kernel<<<512, 256, 0, stream>>>(extra, W_er, er);

  float* outs = out;                              // [128][128][512]
  float* hfin = out + (size_t)BB * TT * HHID;     // [2][128][512]

  for (int l = 0; l < 2; ++l) {
    gemm_gi<<<1536, 256, 0, stream>>>(
        l == 0 ? xb : h0seq,
        WiCat + (size_t)l * 1536 * 512,
        b_ir + (size_t)l * 512, b_iz + (size_t)l * 512, b_in + (size_t)l * 512,
        er + (size_t)l * 128 * 512,
        Gi);
    recur_kernel<<<64, 384, 0, stream>>>(
        WhCat + (size_t)l * 1536 * 512, Gi,
        l == 0 ? h0seq : (f16*)nullptr,
        l == 0 ? (float*)nullptr : outs,
        hfin + (size_t)l * 128 * 512,
        hglob, cnt + l * 8, l);
  }
}

// Round 2
// 926.919 us; speedup vs baseline: 4.3559x; 4.3559x over previous
//
#include <hip/hip_runtime.h>

typedef _Float16 f16;
typedef _Float16 f16x4 __attribute__((ext_vector_type(4)));
typedef _Float16 f16x8 __attribute__((ext_vector_type(8)));
typedef float f32x4 __attribute__((ext_vector_type(4)));
typedef unsigned long long u64;

// dims
#define BB 128
#define TT 128
#define IIN 512
#define HHID 512
#define EEX 256

// ---------------- prep: fp32 -> fp16 conversions + counter reset ----------------
__global__ void prep_kernel(const float* __restrict__ x,
    const float* __restrict__ W_ir, const float* __restrict__ W_iz, const float* __restrict__ W_in,
    const float* __restrict__ W_hr, const float* __restrict__ W_hz, const float* __restrict__ W_hn,
    f16* __restrict__ xb, f16* __restrict__ WiCat, f16* __restrict__ WhCat,
    unsigned* __restrict__ cnt)
{
  size_t idx = (size_t)blockIdx.x * 256 + threadIdx.x;
  if (blockIdx.x == 0 && threadIdx.x < 16)
    __hip_atomic_store(&cnt[threadIdx.x * 32], 0u, __ATOMIC_RELAXED, __HIP_MEMORY_SCOPE_AGENT);

  const size_t NX = (size_t)TT * BB * (IIN / 8);         // 1,048,576 chunks of 8
  const size_t NW = (size_t)2 * 1536 * (512 / 8);        // 196,608 per weight set
  if (idx < NX) {
    int t = (int)(idx / (BB * 64));
    int rem = (int)(idx % (BB * 64));
    int b = rem >> 6;
    int k0 = (rem & 63) * 8;
    const float* src = x + ((size_t)b * TT + t) * IIN + k0;
    f16x8 v;
#pragma unroll
    for (int j = 0; j < 8; ++j) v[j] = (f16)src[j];
    *(f16x8*)(xb + ((size_t)t * BB + b) * IIN + k0) = v;
  } else if (idx < NX + 2 * NW) {
    size_t w = idx - NX;
    bool isI = w < NW;
    size_t w2 = isI ? w : w - NW;
    int l = (int)(w2 / (1536 * 64));
    int rem = (int)(w2 % (1536 * 64));
    int n = rem >> 6;
    int k0 = (rem & 63) * 8;
    int g = n >> 9, j = n & 511;
    const float* W = isI ? (g == 0 ? W_ir : (g == 1 ? W_iz : W_in))
                         : (g == 0 ? W_hr : (g == 1 ? W_hz : W_hn));
    const float* src = W + ((size_t)l * 512 + j) * 512 + k0;
    f16x8 v;
#pragma unroll
    for (int jj = 0; jj < 8; ++jj) v[jj] = (f16)src[jj];
    f16* dst = isI ? WiCat : WhCat;
    *(f16x8*)(dst + ((size_t)l * 1536 + n) * 512 + k0) = v;
  }
}

// ---------------- er[l][b][h] = sum_e extra[b][e] * W_er[l][h][e] (f32) ----------------
__global__ void er_kernel(const float* __restrict__ extra, const float* __restrict__ W_er,
                          float* __restrict__ er)
{
  int idx = blockIdx.x * 256 + threadIdx.x;   // 2*128*512 = 131072
  int l = idx >> 16;
  int b = (idx >> 9) & 127;
  int h = idx & 511;
  const float* e = extra + (size_t)b * EEX;
  const float* w = W_er + ((size_t)l * 512 + h) * EEX;
  float acc = 0.f;
#pragma unroll 4
  for (int k = 0; k < EEX; k += 4)
    acc += e[k] * w[k] + e[k + 1] * w[k + 1] + e[k + 2] * w[k + 2] + e[k + 3] * w[k + 3];
  er[idx] = acc;
}

// ---------------- input-projection GEMM: Gi[m][n] = A[m,:] . Wcat[n,:] + bias + er ----------------
// M=16384 (m = t*128+b), N=1536, K=512. A,Wcat row-major fp16 (K contiguous). Output fp16.
__global__ __launch_bounds__(256, 2) void gemm_gi(
    const f16* __restrict__ A, const f16* __restrict__ Wcat,
    const float* __restrict__ b_r, const float* __restrict__ b_z, const float* __restrict__ b_n,
    const float* __restrict__ er,    // [128][512] this layer
    f16* __restrict__ Gi)            // [16384][1536]
{
  const int tid = threadIdx.x;
  const int wave = tid >> 6, lane = tid & 63;
  const int bm = blockIdx.x % 128, bn = blockIdx.x / 128;  // 128 x 12 tiles
  const int m0 = bm * 128, n0 = bn * 128;
  const int wm = wave >> 1, wn = wave & 1;
  const int r16 = lane & 15, khi = lane >> 4;

  __shared__ f16 As[128 * 40];   // padded stride 40 f16
  __shared__ f16 Bs[128 * 40];

  const f32x4 vzero = {0.f, 0.f, 0.f, 0.f};
  f32x4 acc[4][4];
#pragma unroll
  for (int mi = 0; mi < 4; ++mi)
#pragma unroll
    for (int ni = 0; ni < 4; ++ni) acc[mi][ni] = vzero;

  const int srow = tid >> 1, skoff = (tid & 1) * 16;
  const f16* Aptr = A + (size_t)(m0 + srow) * 512 + skoff;
  const f16* Bptr = Wcat + (size_t)(n0 + srow) * 512 + skoff;

  for (int ks = 0; ks < 512; ks += 32) {
    f16x8 a0 = *(const f16x8*)(Aptr + ks);
    f16x8 a1 = *(const f16x8*)(Aptr + ks + 8);
    f16x8 b0 = *(const f16x8*)(Bptr + ks);
    f16x8 b1 = *(const f16x8*)(Bptr + ks + 8);
    *(f16x8*)(As + srow * 40 + skoff)     = a0;
    *(f16x8*)(As + srow * 40 + skoff + 8) = a1;
    *(f16x8*)(Bs + srow * 40 + skoff)     = b0;
    *(f16x8*)(Bs + srow * 40 + skoff + 8) = b1;
    __syncthreads();
    f16x8 af[4], bf[4];
#pragma unroll
    for (int mi = 0; mi < 4; ++mi)
      af[mi] = *(const f16x8*)(As + (wm * 64 + mi * 16 + r16) * 40 + khi * 8);
#pragma unroll
    for (int ni = 0; ni < 4; ++ni)
      bf[ni] = *(const f16x8*)(Bs + (wn * 64 + ni * 16 + r16) * 40 + khi * 8);
#pragma unroll
    for (int mi = 0; mi < 4; ++mi)
#pragma unroll
      for (int ni = 0; ni < 4; ++ni)
        acc[mi][ni] = __builtin_amdgcn_mfma_f32_16x16x32_f16(af[mi], bf[ni], acc[mi][ni], 0, 0, 0);
    __syncthreads();
  }

  // epilogue: C/D layout col = lane&15, row = (lane>>4)*4 + v  [m89 verified]
#pragma unroll
  for (int mi = 0; mi < 4; ++mi) {
#pragma unroll
    for (int v = 0; v < 4; ++v) {
      int gm = m0 + wm * 64 + mi * 16 + khi * 4 + v;
      int b = gm & 127;
#pragma unroll
      for (int ni = 0; ni < 4; ++ni) {
        int gn = n0 + wn * 64 + ni * 16 + r16;
        int j = gn & 511;
        float bias, add = 0.f;
        if (gn < 512)       { bias = b_r[j]; add = er[(size_t)b * 512 + j]; }
        else if (gn < 1024) { bias = b_z[j]; }
        else                { bias = b_n[j]; }
        float val = acc[mi][ni][v] + bias + add;
        Gi[(size_t)gm * 1536 + gn] = (f16)val;
      }
    }
  }
}

// ---------------- recurrence: 8 clusters (16 rows) x 8 col-slice blocks (64 hid cols) ----------------
// Cross-block exchange via coherence-point (sc-flagged) relaxed agent atomics: NO cache-flushing
// fences (threadfence at agent scope = buffer_wbl2/buffer_inv on gfx950 -> 15us/step; avoided).
__global__ __launch_bounds__(384, 1) void recur_kernel(
    const f16* __restrict__ Whcat,   // [1536][512] this layer
    const f16* __restrict__ Gi,      // [16384][1536] fp16
    f16* __restrict__ h0seq,         // layer0: [T*128][512] out (else null)
    float* __restrict__ outs,        // layer1: d_out [128][T][512] (else null)
    float* __restrict__ hfin,        // d_out tail + layer*128*512
    u64* __restrict__ hglob,         // [2][128][128] u64 exchange (=[2][128][512] f16)
    unsigned* __restrict__ cnt,      // this layer's counters, stride 32 uints per cluster
    int layer)
{
  const int tid = threadIdx.x;
  const int wave = tid >> 6, lane = tid & 63;
  const int cluster = blockIdx.x & 7;   // row group: rows cluster*16..+15
  const int s = blockIdx.x >> 3;        // col slice: hidden cols s*64..+63
  const int r16 = lane & 15, khi = lane >> 4;

  __shared__ f16 hcur[16 * 520];        // padded (520 f16/row)
  __shared__ float pre[12][16][17];     // 12 gate-col tiles, padded -> no 4-way bank conflict
  __shared__ float hf32[16 * 64];       // fp32 master h for own slice

  // ---- weights -> registers (loop-invariant B-fragments), PINNED so the compiler
  // cannot rematerialize the global loads inside the time loop.
  f16x8 wf0[16], wf1[16];
  {
    int tau0 = wave, tau1 = wave + 6;
    const f16* w0 = Whcat + (size_t)((tau0 >> 2) * 512 + s * 64 + (tau0 & 3) * 16 + r16) * 512 + khi * 8;
    const f16* w1 = Whcat + (size_t)((tau1 >> 2) * 512 + s * 64 + (tau1 & 3) * 16 + r16) * 512 + khi * 8;
#pragma unroll
    for (int c = 0; c < 16; ++c) {
      wf0[c] = *(const f16x8*)(w0 + c * 32);
      wf1[c] = *(const f16x8*)(w1 + c * 32);
    }
#pragma unroll
    for (int c = 0; c < 16; ++c)
      asm volatile("" : "+v"(wf0[c]), "+v"(wf1[c]));
  }

  // zero-init h state
  for (int i = tid; i < 16 * 520 / 8; i += 384) {
    f16x8 z;
#pragma unroll
    for (int j = 0; j < 8; ++j) z[j] = (f16)0.f;
    ((f16x8*)hcur)[i] = z;
  }
  for (int i = tid; i < 1024; i += 384) hf32[i] = 0.f;
  __syncthreads();

  // blend mapping: 256 active threads, each owns (row, 4 consecutive cols)
  const int brow = tid >> 4;            // 0..15 (valid when tid<256)
  const int qj = tid & 15;              // col quad: cols qj*4 .. qj*4+3
  const bool act = tid < 256;
  const int gr = cluster * 16 + brow;

  // Gi prefetch (raw f16x4, converted at use so the load can stay in flight)
  f16x4 pga, pgb, pgc;
  if (act) {
    const f16* g = Gi + ((size_t)gr) * 1536 + s * 64 + qj * 4;
    pga = *(const f16x4*)g;
    pgb = *(const f16x4*)(g + 512);
    pgc = *(const f16x4*)(g + 1024);
  }

  for (int t = 0; t < TT; ++t) {
    // ---- MFMA: pre[m, gatecol] = h . Whcat^T ----
    const f32x4 vzero = {0.f, 0.f, 0.f, 0.f};
    f32x4 acc0 = vzero, acc1 = vzero;
#pragma unroll
    for (int c = 0; c < 16; ++c) {
      f16x8 a = *(const f16x8*)(hcur + r16 * 520 + c * 32 + khi * 8);
      acc0 = __builtin_amdgcn_mfma_f32_16x16x32_f16(a, wf0[c], acc0, 0, 0, 0);
      acc1 = __builtin_amdgcn_mfma_f32_16x16x32_f16(a, wf1[c], acc1, 0, 0, 0);
    }
#pragma unroll
    for (int v = 0; v < 4; ++v) {
      pre[wave][khi * 4 + v][r16] = acc0[v];
      pre[wave + 6][khi * 4 + v][r16] = acc1[v];
    }
    __syncthreads();

    // ---- blend: gates + state update; pack 4 cols -> one 8B coherent store ----
    if (act) {
      int nbuf = (t + 1) & 1;
      union { f16 h[4]; u64 u; } pk;
#pragma unroll
      for (int c = 0; c < 4; ++c) {
        int j = qj * 4 + c;
        float pr = pre[j >> 4][brow][j & 15];
        float pz = pre[4 + (j >> 4)][brow][j & 15];
        float pn = pre[8 + (j >> 4)][brow][j & 15];
        float rg = 1.f / (1.f + __expf(-((float)pga[c] + pr)));
        float zg = 1.f / (1.f + __expf(-((float)pgb[c] + pz)));
        float xn = (float)pgc[c] + rg * pn;
        xn = fminf(15.f, fmaxf(-15.f, xn));
        float e2 = __expf(2.f * xn);
        float nn = (e2 - 1.f) / (e2 + 1.f);
        int li = brow * 64 + j;
        float hold = hf32[li];
        float hnew = (1.f - zg) * nn + zg * hold;
        hf32[li] = hnew;
        pk.h[c] = (f16)hnew;
        if (layer == 0)
          h0seq[((size_t)t * 128 + gr) * 512 + s * 64 + j] = (f16)hnew;
        else
          outs[((size_t)gr * TT + t) * 512 + s * 64 + j] = hnew;
        if (t == TT - 1)
          hfin[(size_t)gr * 512 + s * 64 + j] = hnew;
      }
      __hip_atomic_store(hglob + (size_t)nbuf * 16384 + gr * 128 + s * 16 + qj, pk.u,
                         __ATOMIC_RELAXED, __HIP_MEMORY_SCOPE_AGENT);
    }
    if (t == TT - 1) break;

    // own coherent stores retired before arrival flag
    asm volatile("s_waitcnt vmcnt(0)" ::: "memory");

    // ---- prefetch Gi[t+1] (cached loads; stay in flight across the barrier) ----
    if (act) {
      const f16* g = Gi + ((size_t)((t + 1) * 128 + gr)) * 1536 + s * 64 + qj * 4;
      pga = *(const f16x4*)g;
      pgb = *(const f16x4*)(g + 512);
      pgc = *(const f16x4*)(g + 1024);
    }

    // ---- cluster barrier: arrive + poll (all at coherence point, no cache flush) ----
    __syncthreads();   // every wave's h-stores retired
    if (tid == 0) {
      unsigned tgt = 8u * (unsigned)(t + 1);
      __hip_atomic_fetch_add(&cnt[cluster * 32], 1u, __ATOMIC_RELAXED, __HIP_MEMORY_SCOPE_AGENT);
      while (__hip_atomic_load(&cnt[cluster * 32], __ATOMIC_RELAXED, __HIP_MEMORY_SCOPE_AGENT) < tgt)
        __builtin_amdgcn_s_sleep(1);
    }
    __syncthreads();

    // ---- reload full h (16 rows x 512 cols) via coherent loads: issue all, then consume ----
    {
      int nbuf = (t + 1) & 1;
      const u64* hsrc = hglob + (size_t)nbuf * 16384 + (size_t)cluster * 16 * 128;
      u64 vv[6];
#pragma unroll
      for (int u = 0; u < 6; ++u) {
        int i = tid + u * 384;
        if (i < 2048)
          vv[u] = __hip_atomic_load(hsrc + i, __ATOMIC_RELAXED, __HIP_MEMORY_SCOPE_AGENT);
      }
#pragma unroll
      for (int u = 0; u < 6; ++u) {
        int i = tid + u * 384;
        if (i < 2048) {
          int row = i >> 7, q = i & 127;
          *(u64*)(hcur + row * 520 + q * 4) = vv[u];
        }
      }
    }
    __syncthreads();
  }
}

// ---------------- launcher ----------------
extern "C" void kernel_launch(void* const* d_in, const int* in_sizes, int n_in,
                              void* d_out, int out_size, void* d_ws, size_t ws_size,
                              hipStream_t stream) {
  const float* x     = (const float*)d_in[0];
  const float* extra = (const float*)d_in[1];
  const float* W_ir  = (const float*)d_in[2];
  const float* b_ir  = (const float*)d_in[3];
  const float* W_hr  = (const float*)d_in[4];
  const float* W_iz  = (const float*)d_in[5];
  const float* b_iz  = (const float*)d_in[6];
  const float* W_hz  = (const float*)d_in[7];
  const float* W_in  = (const float*)d_in[8];
  const float* b_in  = (const float*)d_in[9];
  const float* W_hn  = (const float*)d_in[10];
  const float* W_er  = (const float*)d_in[11];
  float* out = (float*)d_out;

  char* ws = (char*)d_ws;
  f16* WiCat   = (f16*)(ws);                   // 2*1536*512 fp16 = 3,145,728 B
  f16* WhCat   = (f16*)(ws + 3145728);         // 3,145,728 B
  f16* xb      = (f16*)(ws + 6291456);         // 16,777,216 B
  f16* h0seq   = (f16*)(ws + 23068672);        // 16,777,216 B
  float* er    = (float*)(ws + 39845888);      // 524,288 B
  f16* Gi      = (f16*)(ws + 40370176);        // 16384*1536*2 = 50,331,648 B
  u64* hglob   = (u64*)(ws + 90701824);        // 262,144 B
  unsigned* cnt = (unsigned*)(ws + 90963968);  // 2 layers * 8 clusters * 128B = 2 KB

  prep_kernel<<<5632, 256, 0, stream>>>(x, W_ir, W_iz, W_in, W_hr, W_hz, W_hn,
                                        xb, WiCat, WhCat, cnt);
  er_kernel<<<512, 256, 0, stream>>>(extra, W_er, er);

  float* outs = out;                              // [128][128][512]
  float* hfin = out + (size_t)BB * TT * HHID;     // [2][128][512]

  for (int l = 0; l < 2; ++l) {
    gemm_gi<<<1536, 256, 0, stream>>>(
        l == 0 ? xb : h0seq,
        WiCat + (size_t)l * 1536 * 512,
        b_ir + (size_t)l * 512, b_iz + (size_t)l * 512, b_in + (size_t)l * 512,
        er + (size_t)l * 128 * 512,
        Gi);
    recur_kernel<<<64, 384, 0, stream>>>(
        WhCat + (size_t)l * 1536 * 512, Gi,
        l == 0 ? h0seq : (f16*)nullptr,
        l == 0 ? (float*)nullptr : outs,
        hfin + (size_t)l * 128 * 512,
        hglob, cnt + l * 8 * 32, l);
  }
}